// Round 8
// baseline (322.726 us; speedup 1.0000x reference)
//
#include <hip/hip_runtime.h>
#include <hip/hip_bf16.h>

#define SEQ 2048
#define SCALE 0.125f
#define LOG2E 1.4426950408889634f
// sqrt(2*SCALE*LOG2E): both S operands pre-scaled by this -> S arrives *2*SCALE*LOG2E
#define ALPHA 0.6005612049f

typedef __bf16 bf16;
typedef __bf16 bf16x4 __attribute__((ext_vector_type(4)));
typedef __bf16 bf16x8 __attribute__((ext_vector_type(8)));
typedef _Float16 f16;
typedef _Float16 f16x2 __attribute__((ext_vector_type(2)));
typedef _Float16 f16x4 __attribute__((ext_vector_type(4)));
typedef _Float16 f16x8 __attribute__((ext_vector_type(8)));
typedef float f32x4 __attribute__((ext_vector_type(4)));
typedef unsigned int u32;
typedef unsigned int u32x2 __attribute__((ext_vector_type(2)));
typedef unsigned int u32x4 __attribute__((ext_vector_type(4)));

__device__ __forceinline__ u32 pk_u32(float a, float b) {
    return __builtin_bit_cast(u32, __builtin_amdgcn_cvt_pkrtz(a, b));
}

__device__ __forceinline__ f32x4 mfma_f16_32(f16x8 a, f16x8 b, f32x4 c) {
    return __builtin_amdgcn_mfma_f32_16x16x32_f16(a, b, c, 0, 0, 0);
}

__device__ __forceinline__ void gl_lds16(const void* g, void* l) {
    __builtin_amdgcn_global_load_lds((const __attribute__((address_space(1))) u32*)g,
                                     (__attribute__((address_space(3))) u32*)l, 16, 0, 0);
}

// ---------------- prep kernels ----------------

__global__ __launch_bounds__(256) void k_cast_x(const float4* __restrict__ x,
                                                bf16x4* __restrict__ xb) {
    int t = blockIdx.x * 256 + threadIdx.x;
    float4 f = x[t];
    bf16x4 o;
    o[0] = (bf16)f.x; o[1] = (bf16)f.y; o[2] = (bf16)f.z; o[3] = (bf16)f.w;
    xb[t] = o;
}

// merged 3-way transpose+cast: z=0 Wq->Wqvt, z=1 Wv->Wqvt+1M, z=2 Wo->Wot
__global__ __launch_bounds__(256) void k_transpose_cast3(const float* __restrict__ Wq,
                                                         const float* __restrict__ Wv,
                                                         const float* __restrict__ Wo,
                                                         bf16* __restrict__ Wqvt,
                                                         bf16* __restrict__ Wot) {
    __shared__ float tile[32][33];
    int z = blockIdx.z;
    const float* src = (z == 0) ? Wq : (z == 1) ? Wv : Wo;
    bf16* dst = (z == 0) ? Wqvt : (z == 1) ? (Wqvt + 1024 * 1024) : Wot;
    int bx = blockIdx.x * 32;
    int by = blockIdx.y * 32;
    int tx = threadIdx.x;
    int ty = threadIdx.y;
#pragma unroll
    for (int j = 0; j < 32; j += 8)
        tile[ty + j][tx] = src[(size_t)(by + ty + j) * 1024 + bx + tx];
    __syncthreads();
#pragma unroll
    for (int j = 0; j < 32; j += 8)
        dst[(size_t)(bx + ty + j) * 1024 + by + tx] = (bf16)tile[tx][ty + j];
}

// ---------------- GEMM 1: QV = Xb @ [Wq|Wv] + bias ----------------
// Q blocks: C = A*B^T -> Q[bh][s][dh] stored PRE-SCALED by ALPHA (bf16),
//           QN[bh][s] = -0.5 * ||q_scaled||^2 (ready as exp2 C-init).
// V blocks: swapped operands -> registers hold Vt tiles -> Vt[bh][dh][s] in f16.

__global__ __launch_bounds__(256) void k_gemm_qv(const bf16* __restrict__ Xb,
                                                 const bf16* __restrict__ Wqvt,
                                                 const float* __restrict__ bq,
                                                 const float* __restrict__ bv,
                                                 bf16* __restrict__ Q,
                                                 f16* __restrict__ Vt,
                                                 float* __restrict__ QN) {
    constexpr int K = 1024;
    __shared__ bf16 As[128 * 32];
    __shared__ bf16 Bs[128 * 32];
    int t = threadIdx.x, w = t >> 6, l = t & 63;
    int blockN = blockIdx.x * 128, blockM = blockIdx.y * 128;
    int wm = w & 1, wn = w >> 1;
    int lr = l & 15, quad = l >> 4, q8 = quad * 8;
    int skcol = (l & 3) * 8;
    bool isQ = blockN < 1024;

    f32x4 acc[4][4] = {};
    const bf16* Ab = Xb + (size_t)blockM * K;
    const bf16* Bb = Wqvt + (size_t)blockN * K;

    for (int k0 = 0; k0 < K; k0 += 32) {
#pragma unroll
        for (int c2 = 0; c2 < 2; ++c2) {
            int c = 2 * w + c2;
            int row = c * 16 + (l >> 2);
            gl_lds16(Ab + (size_t)row * K + k0 + skcol, As + c * 512);
            gl_lds16(Bb + (size_t)row * K + k0 + skcol, Bs + c * 512);
        }
        __syncthreads();
        const bf16* Aw = As + wm * 64 * 32;
        const bf16* Bw = Bs + wn * 64 * 32;
        bf16x8 af[4], bfr[4];
#pragma unroll
        for (int mi = 0; mi < 4; ++mi) af[mi] = *(const bf16x8*)(Aw + (mi * 16 + lr) * 32 + q8);
#pragma unroll
        for (int ni = 0; ni < 4; ++ni) bfr[ni] = *(const bf16x8*)(Bw + (ni * 16 + lr) * 32 + q8);
        if (isQ) {
#pragma unroll
            for (int mi = 0; mi < 4; ++mi)
#pragma unroll
                for (int ni = 0; ni < 4; ++ni)
                    acc[mi][ni] = __builtin_amdgcn_mfma_f32_16x16x32_bf16(af[mi], bfr[ni], acc[mi][ni], 0, 0, 0);
        } else {
#pragma unroll
            for (int mi = 0; mi < 4; ++mi)
#pragma unroll
                for (int ni = 0; ni < 4; ++ni)
                    acc[mi][ni] = __builtin_amdgcn_mfma_f32_16x16x32_bf16(bfr[ni], af[mi], acc[mi][ni], 0, 0, 0);
        }
        __syncthreads();
    }

    int colbase = blockN + wn * 64;
    if (isQ) {
        int h = colbase >> 6;
        float bias[4];
#pragma unroll
        for (int ni = 0; ni < 4; ++ni) bias[ni] = bq[colbase + ni * 16 + lr];
#pragma unroll
        for (int mi = 0; mi < 4; ++mi) {
#pragma unroll
            for (int r = 0; r < 4; ++r) {
                int m = blockM + wm * 64 + mi * 16 + quad * 4 + r;
                int b = m >> 11, s = m & 2047;
                int bh = (b << 4) + h;
                float qsq = 0.f;
#pragma unroll
                for (int ni = 0; ni < 4; ++ni) {
                    float v = (acc[mi][ni][r] + bias[ni]) * ALPHA;
                    bf16 vb = (bf16)v;
                    Q[((size_t)bh * SEQ + s) * 64 + ni * 16 + lr] = vb;
                    float vr = (float)vb;
                    qsq += vr * vr;
                }
                qsq += __shfl_xor(qsq, 1);
                qsq += __shfl_xor(qsq, 2);
                qsq += __shfl_xor(qsq, 4);
                qsq += __shfl_xor(qsq, 8);
                if (lr == 0) QN[(size_t)bh * SEQ + s] = -0.5f * qsq;
            }
        }
    } else {
        int h = (colbase - 1024) >> 6;
        int b = blockM >> 11;
        int bh = (b << 4) + h;
        int s_base = (blockM & 2047) + wm * 64;
        const float* bvh = bv + (colbase - 1024);
#pragma unroll
        for (int ni = 0; ni < 4; ++ni) {
#pragma unroll
            for (int r = 0; r < 4; ++r) {
                int dh = ni * 16 + quad * 4 + r;
                float bias = bvh[dh];
#pragma unroll
                for (int mi = 0; mi < 4; ++mi) {
                    int s = s_base + mi * 16 + lr;
                    Vt[((size_t)bh * 64 + dh) * SEQ + s] = (f16)(acc[mi][ni][r] + bias);
                }
            }
        }
    }
}

// ---------------- attention v12 ----------------
// = v10 (83-84us) with V taken OUT of LDS. Pipe accounting showed LDS was the
// hottest pipe (~73% busy: 24 b128 ops/wave-tile x 12cyc). The V fragment a
// lane needs is Vt[di*16+lr][j0+np*32+quad*8..+7] = one contiguous 16B global
// load (L2-resident per XCD thanks to the bh-cluster swizzle) -> 8 direct
// loads/wave-tile replace 8 ds_reads + 2 ds_writes (LDS 24->14 ops, ~-42%).
// V loads issue at tile start; ~200cy L2 latency hides under QK+exp2.
// K staging / BBl / per-np compute schedule byte-identical to v10.

__global__ __launch_bounds__(256, 4) void k_attn(const bf16* __restrict__ Q,
                                                 const f16* __restrict__ Vt,
                                                 const float* __restrict__ QN,
                                                 bf16* __restrict__ AO) {
    __shared__ bf16 Ks[64 * 64];     // xor-swizzled 16B chunks
    __shared__ float BBl[2048];

    int t = threadIdx.x, w = t >> 6, l = t & 63;
    // XCD-cluster swizzle
    int p = blockIdx.x + (blockIdx.y << 4);
    int bh = ((p >> 7) << 3) + (p & 7);
    int i0 = ((p >> 3) & 15) * 128;
    const bf16* Qh = Q + (size_t)bh * SEQ * 64;
    const f16* Vh = Vt + (size_t)bh * 64 * SEQ;
    int lr = l & 15, quad = l >> 4, q8 = quad * 8, lr7 = lr & 7;

    // stage QN (already -0.5*||q'||^2) once
    {
        const float4* QN4 = (const float4*)(QN + (size_t)bh * SEQ);
        float4* BB4 = (float4*)BBl;
        BB4[t] = QN4[t];
        BB4[t + 256] = QN4[t + 256];
    }

    // Q fragments (pre-scaled)
    bf16x8 af[2][2];
#pragma unroll
    for (int mi = 0; mi < 2; ++mi)
#pragma unroll
        for (int kc = 0; kc < 2; ++kc)
            af[mi][kc] = *(const bf16x8*)(Qh + (size_t)(i0 + w * 32 + mi * 16 + lr) * 64 + kc * 32 + q8);

    f32x4 oacc[2][4] = {};
    f32x4 dacc[2] = {};
    const f16x8 ones8 = {(f16)1.f, (f16)1.f, (f16)1.f, (f16)1.f,
                         (f16)1.f, (f16)1.f, (f16)1.f, (f16)1.f};

    // Ks frag offsets (A-operand rows j = ni*16+lr)
    int kb[2];
#pragma unroll
    for (int kc = 0; kc < 2; ++kc) kb[kc] = lr * 64 + (((kc * 4 + quad) ^ lr7) * 8);

    // V direct-load row bases: lane reads Vt row dh=di*16+lr
    const f16* vrow[4];
#pragma unroll
    for (int di = 0; di < 4; ++di) vrow[di] = Vh + (size_t)(di * 16 + lr) * SEQ + q8;

    // K staging decomposition: one swizzled b128 per half-row per thread
    int sr0 = t >> 3, sc = t & 7;
    int sr1 = sr0 + 32;
    int sl0 = sr0 * 64 + ((sc ^ (sr0 & 7)) * 8);
    int sl1 = sr1 * 64 + ((sc ^ (sr1 & 7)) * 8);

    // prefetch first K tile into registers
    u32x4 rk0 = *(const u32x4*)(Qh + (size_t)sr0 * 64 + sc * 8);
    u32x4 rk1 = *(const u32x4*)(Qh + (size_t)sr1 * 64 + sc * 8);

    for (int j0 = 0; j0 < SEQ; j0 += 64) {
        __syncthreads();
        *(u32x4*)(Ks + sl0) = rk0;
        *(u32x4*)(Ks + sl1) = rk1;
        // prefetch next K tile
        int jn = j0 + 64;
        if (jn < SEQ) {
            rk0 = *(const u32x4*)(Qh + (size_t)(jn + sr0) * 64 + sc * 8);
            rk1 = *(const u32x4*)(Qh + (size_t)(jn + sr1) * 64 + sc * 8);
        }
        __syncthreads();

        // issue all V fragment loads for this tile (consumed in PV, latency
        // hidden under QK+exp2)
        u32x4 vt[2][4];  // [np][di]
#pragma unroll
        for (int np = 0; np < 2; ++np)
#pragma unroll
            for (int di = 0; di < 4; ++di)
                vt[np][di] = *(const u32x4*)(vrow[di] + j0 + np * 32);

#pragma unroll
        for (int np = 0; np < 2; ++np) {
            u32 hA[2][2], hB[2][2];   // [ni1][c]: mi=0 -> hA, mi=1 -> hB
#pragma unroll
            for (int ni1 = 0; ni1 < 2; ++ni1) {
                int ni = np * 2 + ni1;
                bf16x8 bk0 = *(const bf16x8*)(Ks + ni * 1024 + kb[0]);
                bf16x8 bk1 = *(const bf16x8*)(Ks + ni * 1024 + kb[1]);
                f32x4 bbt = *(const f32x4*)(BBl + j0 + ni * 16 + quad * 4);
                f32x4 sT0 = bbt, sT1 = bbt;
                sT0 = __builtin_amdgcn_mfma_f32_16x16x32_bf16(bk0, af[0][0], sT0, 0, 0, 0);
                sT0 = __builtin_amdgcn_mfma_f32_16x16x32_bf16(bk1, af[0][1], sT0, 0, 0, 0);
                sT1 = __builtin_amdgcn_mfma_f32_16x16x32_bf16(bk0, af[1][0], sT1, 0, 0, 0);
                sT1 = __builtin_amdgcn_mfma_f32_16x16x32_bf16(bk1, af[1][1], sT1, 0, 0, 0);

                float p00 = __builtin_amdgcn_exp2f(sT0[0]);
                float p01 = __builtin_amdgcn_exp2f(sT0[1]);
                float p02 = __builtin_amdgcn_exp2f(sT0[2]);
                float p03 = __builtin_amdgcn_exp2f(sT0[3]);
                float p10 = __builtin_amdgcn_exp2f(sT1[0]);
                float p11 = __builtin_amdgcn_exp2f(sT1[1]);
                float p12 = __builtin_amdgcn_exp2f(sT1[2]);
                float p13 = __builtin_amdgcn_exp2f(sT1[3]);

                hA[ni1][0] = pk_u32(p00, p01);
                hA[ni1][1] = pk_u32(p02, p03);
                hB[ni1][0] = pk_u32(p10, p11);
                hB[ni1][1] = pk_u32(p12, p13);
            }
            // quad<->reg transpose into K=32 A-fragment layout
            f16x8 F8[2];
            {
                u32 a0 = hA[0][0], b0 = hA[1][0], a1 = hA[0][1], b1 = hA[1][1];
                asm("v_permlane32_swap_b32 %0, %1" : "+v"(a0), "+v"(b0));
                asm("v_permlane16_swap_b32 %0, %1" : "+v"(a0), "+v"(b0));
                asm("v_permlane32_swap_b32 %0, %1" : "+v"(a1), "+v"(b1));
                asm("v_permlane16_swap_b32 %0, %1" : "+v"(a1), "+v"(b1));
                u32x4 fu = {a0, a1, b0, b1};
                F8[0] = __builtin_bit_cast(f16x8, fu);
            }
            {
                u32 a0 = hB[0][0], b0 = hB[1][0], a1 = hB[0][1], b1 = hB[1][1];
                asm("v_permlane32_swap_b32 %0, %1" : "+v"(a0), "+v"(b0));
                asm("v_permlane16_swap_b32 %0, %1" : "+v"(a0), "+v"(b0));
                asm("v_permlane32_swap_b32 %0, %1" : "+v"(a1), "+v"(b1));
                asm("v_permlane16_swap_b32 %0, %1" : "+v"(a1), "+v"(b1));
                u32x4 fu = {a0, a1, b0, b1};
                F8[1] = __builtin_bit_cast(f16x8, fu);
            }

            dacc[0] = mfma_f16_32(F8[0], ones8, dacc[0]);
            dacc[1] = mfma_f16_32(F8[1], ones8, dacc[1]);

#pragma unroll
            for (int di = 0; di < 4; ++di) {
                f16x8 vf8 = __builtin_bit_cast(f16x8, vt[np][di]);
                oacc[0][di] = mfma_f16_32(F8[0], vf8, oacc[0][di]);
                oacc[1][di] = mfma_f16_32(F8[1], vf8, oacc[1][di]);
            }
        }
    }

    // epilogue: dacc[mi][r] holds denom for row i = mi*16 + quad*4 + r (all lr copies)
    int b = bh >> 4, h = bh & 15;
#pragma unroll
    for (int mi = 0; mi < 2; ++mi) {
#pragma unroll
        for (int r = 0; r < 4; ++r) {
            float inv = 1.f / dacc[mi][r];
            int s = i0 + w * 32 + mi * 16 + quad * 4 + r;
#pragma unroll
            for (int di = 0; di < 4; ++di) {
                AO[((size_t)(b * SEQ + s)) * 1024 + h * 64 + di * 16 + lr] = (bf16)(oacc[mi][di][r] * inv);
            }
        }
    }
}

// ---------------- GEMM 3: out = AO @ Wo + bo ----------------
// 128x128 tiles, grid (8,64): proven best (R4; the R5 128x64 retile cost ~11us).

__global__ __launch_bounds__(256) void k_gemm_out(const bf16* __restrict__ AO,
                                                  const bf16* __restrict__ Wot,
                                                  const float* __restrict__ bo,
                                                  float* __restrict__ out) {
    constexpr int K = 1024;
    __shared__ bf16 As[128 * 32];
    __shared__ bf16 Bs[128 * 32];
    int t = threadIdx.x, w = t >> 6, l = t & 63;
    int blockN = blockIdx.x * 128, blockM = blockIdx.y * 128;
    int wm = w & 1, wn = w >> 1;
    int lr = l & 15, quad = l >> 4, q8 = quad * 8;
    int skcol = (l & 3) * 8;

    f32x4 acc[4][4] = {};
    const bf16* Ab = AO + (size_t)blockM * K;
    const bf16* Bb = Wot + (size_t)blockN * K;

    for (int k0 = 0; k0 < K; k0 += 32) {
#pragma unroll
        for (int c2 = 0; c2 < 2; ++c2) {
            int c = 2 * w + c2;
            int row = c * 16 + (l >> 2);
            gl_lds16(Ab + (size_t)row * K + k0 + skcol, As + c * 512);
            gl_lds16(Bb + (size_t)row * K + k0 + skcol, Bs + c * 512);
        }
        __syncthreads();
        const bf16* Aw = As + wm * 64 * 32;
        const bf16* Bw = Bs + wn * 64 * 32;
        bf16x8 af[4], bfr[4];
#pragma unroll
        for (int mi = 0; mi < 4; ++mi) af[mi] = *(const bf16x8*)(Aw + (mi * 16 + lr) * 32 + q8);
#pragma unroll
        for (int ni = 0; ni < 4; ++ni) bfr[ni] = *(const bf16x8*)(Bw + (ni * 16 + lr) * 32 + q8);
#pragma unroll
        for (int mi = 0; mi < 4; ++mi)
#pragma unroll
            for (int ni = 0; ni < 4; ++ni)
                acc[mi][ni] = __builtin_amdgcn_mfma_f32_16x16x32_bf16(af[mi], bfr[ni], acc[mi][ni], 0, 0, 0);
        __syncthreads();
    }

    int colbase = blockN + wn * 64;
    float bias[4];
#pragma unroll
    for (int ni = 0; ni < 4; ++ni) bias[ni] = bo[colbase + ni * 16 + lr];
#pragma unroll
    for (int mi = 0; mi < 4; ++mi) {
#pragma unroll
        for (int r = 0; r < 4; ++r) {
            int m = blockM + wm * 64 + mi * 16 + quad * 4 + r;
#pragma unroll
            for (int ni = 0; ni < 4; ++ni) {
                out[(size_t)m * 1024 + colbase + ni * 16 + lr] = acc[mi][ni][r] + bias[ni];
            }
        }
    }
}

// ---------------- launch ----------------

extern "C" void kernel_launch(void* const* d_in, const int* in_sizes, int n_in,
                              void* d_out, int out_size, void* d_ws, size_t ws_size,
                              hipStream_t stream) {
    const float* x  = (const float*)d_in[0];
    const float* Wq = (const float*)d_in[1];
    const float* bq = (const float*)d_in[2];
    const float* Wv = (const float*)d_in[3];
    const float* bv = (const float*)d_in[4];
    const float* Wo = (const float*)d_in[5];
    const float* bo = (const float*)d_in[6];
    float* out = (float*)d_out;

    char* ws = (char*)d_ws;
    bf16* Xb   = (bf16*)ws;                          // 16 MB (reused as AO)
    bf16* Wqvt = (bf16*)(ws + (size_t)(16 << 20));   // 4 MB
    bf16* Wot  = (bf16*)(ws + (size_t)(20 << 20));   // 2 MB
    bf16* Qb   = (bf16*)(ws + (size_t)(22 << 20));   // 16 MB
    f16*  Vtb  = (f16*)(ws + (size_t)(38 << 20));    // 16 MB
    float* QN  = (float*)(ws + (size_t)(54 << 20));  // 0.5 MB
    bf16* AO   = Xb;

    k_cast_x<<<8192, 256, 0, stream>>>((const float4*)x, (bf16x4*)Xb);
    dim3 tb(32, 8);
    k_transpose_cast3<<<dim3(32, 32, 3), tb, 0, stream>>>(Wq, Wv, Wo, Wqvt, Wot);
    k_gemm_qv<<<dim3(16, 64), 256, 0, stream>>>(Xb, Wqvt, bq, bv, Qb, Vtb, QN);
    k_attn<<<dim3(16, 64), 256, 0, stream>>>(Qb, Vtb, QN, AO);
    k_gemm_out<<<dim3(8, 64), 256, 0, stream>>>(AO, Wot, bo, out);
}

// Round 9
// 259.594 us; speedup vs baseline: 1.2432x; 1.2432x over previous
//
#include <hip/hip_runtime.h>
#include <hip/hip_bf16.h>

#define SEQ 2048
#define SCALE 0.125f
#define LOG2E 1.4426950408889634f
// sqrt(2*SCALE*LOG2E): both S operands pre-scaled by this -> S arrives *2*SCALE*LOG2E
#define ALPHA 0.6005612049f

typedef __bf16 bf16;
typedef __bf16 bf16x4 __attribute__((ext_vector_type(4)));
typedef __bf16 bf16x8 __attribute__((ext_vector_type(8)));
typedef _Float16 f16;
typedef _Float16 f16x2 __attribute__((ext_vector_type(2)));
typedef _Float16 f16x4 __attribute__((ext_vector_type(4)));
typedef _Float16 f16x8 __attribute__((ext_vector_type(8)));
typedef float f32x4 __attribute__((ext_vector_type(4)));
typedef unsigned int u32;
typedef unsigned int u32x2 __attribute__((ext_vector_type(2)));
typedef unsigned int u32x4 __attribute__((ext_vector_type(4)));

__device__ __forceinline__ u32 pk_u32(float a, float b) {
    return __builtin_bit_cast(u32, __builtin_amdgcn_cvt_pkrtz(a, b));
}

__device__ __forceinline__ f32x4 mfma_f16_32(f16x8 a, f16x8 b, f32x4 c) {
    return __builtin_amdgcn_mfma_f32_16x16x32_f16(a, b, c, 0, 0, 0);
}

__device__ __forceinline__ void gl_lds16(const void* g, void* l) {
    __builtin_amdgcn_global_load_lds((const __attribute__((address_space(1))) u32*)g,
                                     (__attribute__((address_space(3))) u32*)l, 16, 0, 0);
}

// ---------------- prep kernel (merged cast + 3-way transpose) ----------------
// z=0 Wq->Wqvt, z=1 Wv->Wqvt+1M, z=2 Wo->Wot, z=3 cast x->Xb (grid-stride)

__global__ __launch_bounds__(256) void k_prep(const float* __restrict__ Wq,
                                              const float* __restrict__ Wv,
                                              const float* __restrict__ Wo,
                                              const float4* __restrict__ x,
                                              bf16* __restrict__ Wqvt,
                                              bf16* __restrict__ Wot,
                                              bf16x4* __restrict__ xb) {
    int z = blockIdx.z;
    int tx = threadIdx.x;
    int ty = threadIdx.y;
    if (z == 3) {
        int bid = blockIdx.y * 32 + blockIdx.x;
        int t = ty * 32 + tx;
#pragma unroll
        for (int it = 0; it < 8; ++it) {
            int idx = (bid * 8 + it) * 256 + t;
            float4 f = x[idx];
            bf16x4 o;
            o[0] = (bf16)f.x; o[1] = (bf16)f.y; o[2] = (bf16)f.z; o[3] = (bf16)f.w;
            xb[idx] = o;
        }
        return;
    }
    __shared__ float tile[32][33];
    const float* src = (z == 0) ? Wq : (z == 1) ? Wv : Wo;
    bf16* dst = (z == 0) ? Wqvt : (z == 1) ? (Wqvt + 1024 * 1024) : Wot;
    int bx = blockIdx.x * 32;
    int by = blockIdx.y * 32;
#pragma unroll
    for (int j = 0; j < 32; j += 8)
        tile[ty + j][tx] = src[(size_t)(by + ty + j) * 1024 + bx + tx];
    __syncthreads();
#pragma unroll
    for (int j = 0; j < 32; j += 8)
        dst[(size_t)(bx + ty + j) * 1024 + by + tx] = (bf16)tile[tx][ty + j];
}

// ---------------- GEMM 1: QV = Xb @ [Wq|Wv] + bias ----------------
// Q blocks: C = A*B^T -> Q[bh][s][dh] stored PRE-SCALED by ALPHA (bf16),
//           QN[bh][s] = -0.5 * ||q_scaled||^2 (ready as exp2 C-init).
// V blocks: swapped operands -> registers hold Vt tiles -> Vt[bh][dh][s] in f16.
// XCD row-cluster swizzle: each XCD owns whole blockM-rows -> A-panel fetched
// once per row (vs 8x when blockN spread across XCDs); B 4MB L2-resident.

__global__ __launch_bounds__(256) void k_gemm_qv(const bf16* __restrict__ Xb,
                                                 const bf16* __restrict__ Wqvt,
                                                 const float* __restrict__ bq,
                                                 const float* __restrict__ bv,
                                                 bf16* __restrict__ Q,
                                                 f16* __restrict__ Vt,
                                                 float* __restrict__ QN) {
    constexpr int K = 1024;
    __shared__ bf16 As[128 * 32];
    __shared__ bf16 Bs[128 * 32];
    int t = threadIdx.x, w = t >> 6, l = t & 63;
    // XCD row-cluster swizzle: p mod 8 = XCD; XCD k gets y in {k, k+8, ...}
    int p = blockIdx.x + (blockIdx.y << 4);
    int xk = p & 7, o = p >> 3;
    int bx = o & 15, by = xk + ((o >> 4) << 3);
    int blockN = bx * 128, blockM = by * 128;
    int wm = w & 1, wn = w >> 1;
    int lr = l & 15, quad = l >> 4, q8 = quad * 8;
    int skcol = (l & 3) * 8;
    bool isQ = blockN < 1024;

    f32x4 acc[4][4] = {};
    const bf16* Ab = Xb + (size_t)blockM * K;
    const bf16* Bb = Wqvt + (size_t)blockN * K;

    for (int k0 = 0; k0 < K; k0 += 32) {
#pragma unroll
        for (int c2 = 0; c2 < 2; ++c2) {
            int c = 2 * w + c2;
            int row = c * 16 + (l >> 2);
            gl_lds16(Ab + (size_t)row * K + k0 + skcol, As + c * 512);
            gl_lds16(Bb + (size_t)row * K + k0 + skcol, Bs + c * 512);
        }
        __syncthreads();
        const bf16* Aw = As + wm * 64 * 32;
        const bf16* Bw = Bs + wn * 64 * 32;
        bf16x8 af[4], bfr[4];
#pragma unroll
        for (int mi = 0; mi < 4; ++mi) af[mi] = *(const bf16x8*)(Aw + (mi * 16 + lr) * 32 + q8);
#pragma unroll
        for (int ni = 0; ni < 4; ++ni) bfr[ni] = *(const bf16x8*)(Bw + (ni * 16 + lr) * 32 + q8);
        if (isQ) {
#pragma unroll
            for (int mi = 0; mi < 4; ++mi)
#pragma unroll
                for (int ni = 0; ni < 4; ++ni)
                    acc[mi][ni] = __builtin_amdgcn_mfma_f32_16x16x32_bf16(af[mi], bfr[ni], acc[mi][ni], 0, 0, 0);
        } else {
#pragma unroll
            for (int mi = 0; mi < 4; ++mi)
#pragma unroll
                for (int ni = 0; ni < 4; ++ni)
                    acc[mi][ni] = __builtin_amdgcn_mfma_f32_16x16x32_bf16(bfr[ni], af[mi], acc[mi][ni], 0, 0, 0);
        }
        __syncthreads();
    }

    int colbase = blockN + wn * 64;
    if (isQ) {
        int h = colbase >> 6;
        float bias[4];
#pragma unroll
        for (int ni = 0; ni < 4; ++ni) bias[ni] = bq[colbase + ni * 16 + lr];
#pragma unroll
        for (int mi = 0; mi < 4; ++mi) {
#pragma unroll
            for (int r = 0; r < 4; ++r) {
                int m = blockM + wm * 64 + mi * 16 + quad * 4 + r;
                int b = m >> 11, s = m & 2047;
                int bh = (b << 4) + h;
                float qsq = 0.f;
#pragma unroll
                for (int ni = 0; ni < 4; ++ni) {
                    float v = (acc[mi][ni][r] + bias[ni]) * ALPHA;
                    bf16 vb = (bf16)v;
                    Q[((size_t)bh * SEQ + s) * 64 + ni * 16 + lr] = vb;
                    float vr = (float)vb;
                    qsq += vr * vr;
                }
                qsq += __shfl_xor(qsq, 1);
                qsq += __shfl_xor(qsq, 2);
                qsq += __shfl_xor(qsq, 4);
                qsq += __shfl_xor(qsq, 8);
                if (lr == 0) QN[(size_t)bh * SEQ + s] = -0.5f * qsq;
            }
        }
    } else {
        int h = (colbase - 1024) >> 6;
        int b = blockM >> 11;
        int bh = (b << 4) + h;
        int s_base = (blockM & 2047) + wm * 64;
        const float* bvh = bv + (colbase - 1024);
#pragma unroll
        for (int ni = 0; ni < 4; ++ni) {
#pragma unroll
            for (int r = 0; r < 4; ++r) {
                int dh = ni * 16 + quad * 4 + r;
                float bias = bvh[dh];
#pragma unroll
                for (int mi = 0; mi < 4; ++mi) {
                    int s = s_base + mi * 16 + lr;
                    Vt[((size_t)bh * 64 + dh) * SEQ + s] = (f16)(acc[mi][ni][r] + bias);
                }
            }
        }
    }
}

// ---------------- attention v10 (proven: 83-84.5us, R5/R7) ----------------
// = v6 + XCD bh-cluster swizzle ONLY. All schedule variants (v7,v8,v9,v11,v12)
// regressed or raced -> this structure is frozen.

__global__ __launch_bounds__(256, 4) void k_attn(const bf16* __restrict__ Q,
                                                 const f16* __restrict__ Vt,
                                                 const float* __restrict__ QN,
                                                 bf16* __restrict__ AO) {
    __shared__ bf16 Ks[64 * 64];     // xor-swizzled 16B chunks
    __shared__ f16 Vs[64 * 64];      // contiguous-j chunks, xor-swizzled
    __shared__ float BBl[2048];

    int t = threadIdx.x, w = t >> 6, l = t & 63;
    // XCD-cluster swizzle
    int p = blockIdx.x + (blockIdx.y << 4);
    int bh = ((p >> 7) << 3) + (p & 7);
    int i0 = ((p >> 3) & 15) * 128;
    const bf16* Qh = Q + (size_t)bh * SEQ * 64;
    const f16* Vh = Vt + (size_t)bh * 64 * SEQ;
    int lr = l & 15, quad = l >> 4, q8 = quad * 8, lr7 = lr & 7;

    // stage QN (already -0.5*||q'||^2) once
    {
        const float4* QN4 = (const float4*)(QN + (size_t)bh * SEQ);
        float4* BB4 = (float4*)BBl;
        BB4[t] = QN4[t];
        BB4[t + 256] = QN4[t + 256];
    }

    // Q fragments (pre-scaled)
    bf16x8 af[2][2];
#pragma unroll
    for (int mi = 0; mi < 2; ++mi)
#pragma unroll
        for (int kc = 0; kc < 2; ++kc)
            af[mi][kc] = *(const bf16x8*)(Qh + (size_t)(i0 + w * 32 + mi * 16 + lr) * 64 + kc * 32 + q8);

    f32x4 oacc[2][4] = {};
    f32x4 dacc[2] = {};
    const f16x8 ones8 = {(f16)1.f, (f16)1.f, (f16)1.f, (f16)1.f,
                         (f16)1.f, (f16)1.f, (f16)1.f, (f16)1.f};

    // Ks frag offsets (A-operand rows j = ni*16+lr)
    int kb[2];
#pragma unroll
    for (int kc = 0; kc < 2; ++kc) kb[kc] = lr * 64 + (((kc * 4 + quad) ^ lr7) * 8);
    // Vs frag offsets: row (di*16+lr), chunk (np*4+quad)^lr7  (j = np*32+quad*8+{0..7})
    int voff[4];
#pragma unroll
    for (int di = 0; di < 4; ++di) voff[di] = (di * 16 + lr) * 64;
    int npo[2];
#pragma unroll
    for (int np = 0; np < 2; ++np) npo[np] = ((np * 4 + quad) ^ lr7) * 8;

    // staging decomposition: both Ks and Vs take one swizzled b128 per half-row
    int sr0 = t >> 3, sc = t & 7;
    int sr1 = sr0 + 32;
    int sl0 = sr0 * 64 + ((sc ^ (sr0 & 7)) * 8);
    int sl1 = sr1 * 64 + ((sc ^ (sr1 & 7)) * 8);

    // prefetch first tile into registers
    u32x4 rk0 = *(const u32x4*)(Qh + (size_t)sr0 * 64 + sc * 8);
    u32x4 rk1 = *(const u32x4*)(Qh + (size_t)sr1 * 64 + sc * 8);
    u32x4 rv0 = *(const u32x4*)(Vh + (size_t)sr0 * SEQ + sc * 8);
    u32x4 rv1 = *(const u32x4*)(Vh + (size_t)sr1 * SEQ + sc * 8);

    for (int j0 = 0; j0 < SEQ; j0 += 64) {
        __syncthreads();
        *(u32x4*)(Ks + sl0) = rk0;
        *(u32x4*)(Ks + sl1) = rk1;
        *(u32x4*)(Vs + sl0) = rv0;
        *(u32x4*)(Vs + sl1) = rv1;
        // prefetch next tile
        int jn = j0 + 64;
        if (jn < SEQ) {
            rk0 = *(const u32x4*)(Qh + (size_t)(jn + sr0) * 64 + sc * 8);
            rk1 = *(const u32x4*)(Qh + (size_t)(jn + sr1) * 64 + sc * 8);
            rv0 = *(const u32x4*)(Vh + (size_t)sr0 * SEQ + jn + sc * 8);
            rv1 = *(const u32x4*)(Vh + (size_t)sr1 * SEQ + jn + sc * 8);
        }
        __syncthreads();

#pragma unroll
        for (int np = 0; np < 2; ++np) {
            u32 hA[2][2], hB[2][2];   // [ni1][c]: mi=0 -> hA, mi=1 -> hB
#pragma unroll
            for (int ni1 = 0; ni1 < 2; ++ni1) {
                int ni = np * 2 + ni1;
                bf16x8 bk0 = *(const bf16x8*)(Ks + ni * 1024 + kb[0]);
                bf16x8 bk1 = *(const bf16x8*)(Ks + ni * 1024 + kb[1]);
                f32x4 bbt = *(const f32x4*)(BBl + j0 + ni * 16 + quad * 4);
                f32x4 sT0 = bbt, sT1 = bbt;
                sT0 = __builtin_amdgcn_mfma_f32_16x16x32_bf16(bk0, af[0][0], sT0, 0, 0, 0);
                sT0 = __builtin_amdgcn_mfma_f32_16x16x32_bf16(bk1, af[0][1], sT0, 0, 0, 0);
                sT1 = __builtin_amdgcn_mfma_f32_16x16x32_bf16(bk0, af[1][0], sT1, 0, 0, 0);
                sT1 = __builtin_amdgcn_mfma_f32_16x16x32_bf16(bk1, af[1][1], sT1, 0, 0, 0);

                float p00 = __builtin_amdgcn_exp2f(sT0[0]);
                float p01 = __builtin_amdgcn_exp2f(sT0[1]);
                float p02 = __builtin_amdgcn_exp2f(sT0[2]);
                float p03 = __builtin_amdgcn_exp2f(sT0[3]);
                float p10 = __builtin_amdgcn_exp2f(sT1[0]);
                float p11 = __builtin_amdgcn_exp2f(sT1[1]);
                float p12 = __builtin_amdgcn_exp2f(sT1[2]);
                float p13 = __builtin_amdgcn_exp2f(sT1[3]);

                hA[ni1][0] = pk_u32(p00, p01);
                hA[ni1][1] = pk_u32(p02, p03);
                hB[ni1][0] = pk_u32(p10, p11);
                hB[ni1][1] = pk_u32(p12, p13);
            }
            // quad<->reg transpose into K=32 A-fragment layout
            f16x8 F8[2];
            {
                u32 a0 = hA[0][0], b0 = hA[1][0], a1 = hA[0][1], b1 = hA[1][1];
                asm("v_permlane32_swap_b32 %0, %1" : "+v"(a0), "+v"(b0));
                asm("v_permlane16_swap_b32 %0, %1" : "+v"(a0), "+v"(b0));
                asm("v_permlane32_swap_b32 %0, %1" : "+v"(a1), "+v"(b1));
                asm("v_permlane16_swap_b32 %0, %1" : "+v"(a1), "+v"(b1));
                u32x4 fu = {a0, a1, b0, b1};
                F8[0] = __builtin_bit_cast(f16x8, fu);
            }
            {
                u32 a0 = hB[0][0], b0 = hB[1][0], a1 = hB[0][1], b1 = hB[1][1];
                asm("v_permlane32_swap_b32 %0, %1" : "+v"(a0), "+v"(b0));
                asm("v_permlane16_swap_b32 %0, %1" : "+v"(a0), "+v"(b0));
                asm("v_permlane32_swap_b32 %0, %1" : "+v"(a1), "+v"(b1));
                asm("v_permlane16_swap_b32 %0, %1" : "+v"(a1), "+v"(b1));
                u32x4 fu = {a0, a1, b0, b1};
                F8[1] = __builtin_bit_cast(f16x8, fu);
            }

            dacc[0] = mfma_f16_32(F8[0], ones8, dacc[0]);
            dacc[1] = mfma_f16_32(F8[1], ones8, dacc[1]);

#pragma unroll
            for (int di = 0; di < 4; ++di) {
                f16x8 vf8 = *(const f16x8*)(Vs + voff[di] + npo[np]);
                oacc[0][di] = mfma_f16_32(F8[0], vf8, oacc[0][di]);
                oacc[1][di] = mfma_f16_32(F8[1], vf8, oacc[1][di]);
            }
        }
    }

    // epilogue: dacc[mi][r] holds denom for row i = mi*16 + quad*4 + r (all lr copies)
    int b = bh >> 4, h = bh & 15;
#pragma unroll
    for (int mi = 0; mi < 2; ++mi) {
#pragma unroll
        for (int r = 0; r < 4; ++r) {
            float inv = 1.f / dacc[mi][r];
            int s = i0 + w * 32 + mi * 16 + quad * 4 + r;
#pragma unroll
            for (int di = 0; di < 4; ++di) {
                AO[((size_t)(b * SEQ + s)) * 1024 + h * 64 + di * 16 + lr] = (bf16)(oacc[mi][di][r] * inv);
            }
        }
    }
}

// ---------------- GEMM 3: out = AO @ Wo + bo ----------------
// 128x128 tiles, grid (8,64) + XCD row-cluster swizzle (A-panel fetched once
// per row per XCD instead of 8x; B 2MB L2-resident).

__global__ __launch_bounds__(256) void k_gemm_out(const bf16* __restrict__ AO,
                                                  const bf16* __restrict__ Wot,
                                                  const float* __restrict__ bo,
                                                  float* __restrict__ out) {
    constexpr int K = 1024;
    __shared__ bf16 As[128 * 32];
    __shared__ bf16 Bs[128 * 32];
    int t = threadIdx.x, w = t >> 6, l = t & 63;
    // XCD row-cluster swizzle: p mod 8 = XCD; XCD k gets y in {k, k+8, ...}
    int p = blockIdx.x + (blockIdx.y << 3);
    int xk = p & 7, o = p >> 3;
    int bx = o & 7, by = xk + ((o >> 3) << 3);
    int blockN = bx * 128, blockM = by * 128;
    int wm = w & 1, wn = w >> 1;
    int lr = l & 15, quad = l >> 4, q8 = quad * 8;
    int skcol = (l & 3) * 8;

    f32x4 acc[4][4] = {};
    const bf16* Ab = AO + (size_t)blockM * K;
    const bf16* Bb = Wot + (size_t)blockN * K;

    for (int k0 = 0; k0 < K; k0 += 32) {
#pragma unroll
        for (int c2 = 0; c2 < 2; ++c2) {
            int c = 2 * w + c2;
            int row = c * 16 + (l >> 2);
            gl_lds16(Ab + (size_t)row * K + k0 + skcol, As + c * 512);
            gl_lds16(Bb + (size_t)row * K + k0 + skcol, Bs + c * 512);
        }
        __syncthreads();
        const bf16* Aw = As + wm * 64 * 32;
        const bf16* Bw = Bs + wn * 64 * 32;
        bf16x8 af[4], bfr[4];
#pragma unroll
        for (int mi = 0; mi < 4; ++mi) af[mi] = *(const bf16x8*)(Aw + (mi * 16 + lr) * 32 + q8);
#pragma unroll
        for (int ni = 0; ni < 4; ++ni) bfr[ni] = *(const bf16x8*)(Bw + (ni * 16 + lr) * 32 + q8);
#pragma unroll
        for (int mi = 0; mi < 4; ++mi)
#pragma unroll
            for (int ni = 0; ni < 4; ++ni)
                acc[mi][ni] = __builtin_amdgcn_mfma_f32_16x16x32_bf16(af[mi], bfr[ni], acc[mi][ni], 0, 0, 0);
        __syncthreads();
    }

    int colbase = blockN + wn * 64;
    float bias[4];
#pragma unroll
    for (int ni = 0; ni < 4; ++ni) bias[ni] = bo[colbase + ni * 16 + lr];
#pragma unroll
    for (int mi = 0; mi < 4; ++mi) {
#pragma unroll
        for (int r = 0; r < 4; ++r) {
            int m = blockM + wm * 64 + mi * 16 + quad * 4 + r;
#pragma unroll
            for (int ni = 0; ni < 4; ++ni) {
                out[(size_t)m * 1024 + colbase + ni * 16 + lr] = acc[mi][ni][r] + bias[ni];
            }
        }
    }
}

// ---------------- launch ----------------

extern "C" void kernel_launch(void* const* d_in, const int* in_sizes, int n_in,
                              void* d_out, int out_size, void* d_ws, size_t ws_size,
                              hipStream_t stream) {
    const float* x  = (const float*)d_in[0];
    const float* Wq = (const float*)d_in[1];
    const float* bq = (const float*)d_in[2];
    const float* Wv = (const float*)d_in[3];
    const float* bv = (const float*)d_in[4];
    const float* Wo = (const float*)d_in[5];
    const float* bo = (const float*)d_in[6];
    float* out = (float*)d_out;

    char* ws = (char*)d_ws;
    bf16* Xb   = (bf16*)ws;                          // 16 MB (reused as AO)
    bf16* Wqvt = (bf16*)(ws + (size_t)(16 << 20));   // 4 MB
    bf16* Wot  = (bf16*)(ws + (size_t)(20 << 20));   // 2 MB
    bf16* Qb   = (bf16*)(ws + (size_t)(22 << 20));   // 16 MB
    f16*  Vtb  = (f16*)(ws + (size_t)(38 << 20));    // 16 MB
    float* QN  = (float*)(ws + (size_t)(54 << 20));  // 0.5 MB
    bf16* AO   = Xb;

    dim3 tb(32, 8);
    k_prep<<<dim3(32, 32, 4), tb, 0, stream>>>(Wq, Wv, Wo, (const float4*)x,
                                               Wqvt, Wot, (bf16x4*)Xb);
    k_gemm_qv<<<dim3(16, 64), 256, 0, stream>>>(Xb, Wqvt, bq, bv, Qb, Vtb, QN);
    k_attn<<<dim3(16, 64), 256, 0, stream>>>(Qb, Vtb, QN, AO);
    k_gemm_out<<<dim3(8, 64), 256, 0, stream>>>(AO, Wot, bo, out);
}